// Round 12
// baseline (8101.436 us; speedup 1.0000x reference)
//
#include <hip/hip_runtime.h>
#include <hip/hip_bf16.h>
#include <cfloat>

// FPS matching the np reference bit-exactly (R7: PASS, absmax 0).
// FROZEN per-point arithmetic: dx=px-cx; y2=dy*dy; inner=fma(dx,dx,y2);
// d=fma(dz,dz,inner); nd=fminf(dist,d); winner=(max value, smallest index).
// R12: active CUs are ~94% VALU-busy (global 11.7% x 256/32 CUs) => cut
// instructions. Points paired (i, i+8192) into float2 lanes so the frozen
// chain lowers to v_pk_{add,mul,fma}_f32 (bit-exact per half); value-only
// f32 butterflies replace u64 ones; cross-wave scan -> 4-level butterfly.

typedef float v2f __attribute__((ext_vector_type(2)));

#define FPS_THREADS 1024
#define REP8(M) M(0) M(1) M(2) M(3) M(4) M(5) M(6) M(7)

__global__ __launch_bounds__(FPS_THREADS, 4) void fps_kernel(
    const float* __restrict__ xyz, int* __restrict__ out_idx,
    int N, int S) {
#pragma clang fp contract(off)
  const int b = blockIdx.x;
  const int t = threadIdx.x;
  const float* xb = xyz + (size_t)b * N * 3;

  __shared__ v2f s_xp[8192];   // {x_i, x_{i+8192}}
  __shared__ v2f s_yp[8192];   // {y_i, y_{i+8192}}
  __shared__ unsigned long long s_k[2][FPS_THREADS / 64];

#define DECLP(k) v2f pz##k, ds##k; unsigned iv##k;
  REP8(DECLP)

#define LOADP(k) { int p = (k) * FPS_THREADS + t; int q = p + 8192;   \
    float x0 = xb[(size_t)p*3+0], y0 = xb[(size_t)p*3+1], z0 = xb[(size_t)p*3+2]; \
    float x1 = xb[(size_t)q*3+0], y1 = xb[(size_t)q*3+1], z1 = xb[(size_t)q*3+2]; \
    s_xp[p] = (v2f){x0, x1}; s_yp[p] = (v2f){y0, y1};                 \
    pz##k = (v2f){z0, z1}; ds##k = (v2f){FLT_MAX, FLT_MAX};           \
    iv##k = 0xFFFFFFFFu - (unsigned)p; }
  REP8(LOADP)

  const int wave = t >> 6;
  const int lane = t & 63;
  int farthest = 0;

  __syncthreads();  // s_xp/s_yp visible

  for (int s = 0; s < S; ++s) {
    if (t == 0) out_idx[(size_t)b * S + s] = farthest;

    int f = __builtin_amdgcn_readfirstlane(farthest);
    float cz = xb[(size_t)f * 3 + 2];     // early scalar global; used last
    int fl = f & 8191;
    int hi = f >> 13;
    v2f cxp = s_xp[fl], cyp = s_yp[fl];
    float cx = hi ? cxp[1] : cxp[0];
    float cy = hi ? cyp[1] : cyp[0];
    v2f cx2 = (v2f){cx, cx}, cy2 = (v2f){cy, cy}, cz2 = (v2f){cz, cz};

    float bv0 = -1.0f, bv1 = -1.0f;
    unsigned bi0 = 0, bi1 = 0;

    // FROZEN chain, packed 2 points/op (halves are points p and p+8192):
#define STEPP(k) {                                           \
    int p = (k) * FPS_THREADS + t;                           \
    v2f X = s_xp[p], Y = s_yp[p];                            \
    v2f dx = X - cx2;                                        \
    v2f dy = Y - cy2;                                        \
    v2f dz = pz##k - cz2;                                    \
    v2f y2 = dy * dy;                                        \
    v2f inner = __builtin_elementwise_fma(dx, dx, y2);       \
    v2f dd = __builtin_elementwise_fma(dz, dz, inner);       \
    v2f nd = __builtin_elementwise_min(ds##k, dd);           \
    ds##k = nd;                                              \
    if (nd[0] > bv0) { bv0 = nd[0]; bi0 = iv##k; }           \
    if (nd[1] > bv1) { bv1 = nd[1]; bi1 = iv##k; } }
    REP8(STEPP)

    // combine halves: half1 true inv = bi1 - 8192; strict > => ties pick
    // half0 (smaller point index). Within-half ascending k + strict > =
    // first occurrence. Matches reference tie-break exactly.
    float bestv; unsigned bestinv;
    if (bv1 > bv0) { bestv = bv1; bestinv = bi1 - 8192u; }
    else           { bestv = bv0; bestinv = bi0; }

    // wave reduce: value-only max butterfly, then masked inv-max butterfly
    float wv = bestv;
#pragma unroll
    for (int off = 32; off > 0; off >>= 1)
      wv = fmaxf(wv, __shfl_xor(wv, off, 64));
    unsigned ci = (bestv == wv) ? bestinv : 0u;
#pragma unroll
    for (int off = 32; off > 0; off >>= 1) {
      unsigned oi = (unsigned)__shfl_xor((int)ci, off, 64);
      if (oi > ci) ci = oi;
    }

    const int par = s & 1;
    if (lane == 0)
      s_k[par][wave] = ((unsigned long long)__float_as_uint(wv) << 32) |
                       (unsigned long long)ci;
    __syncthreads();

    // cross-wave: 16 keys -> per-lane slot + 4-level u64 butterfly
    unsigned long long bk = s_k[par][lane & 15];
#pragma unroll
    for (int off = 8; off > 0; off >>= 1) {
      unsigned long long ok = __shfl_xor(bk, off, 64);
      if (ok > bk) bk = ok;
    }
    farthest = (int)(0xFFFFFFFFu - (unsigned)(bk & 0xFFFFFFFFu));
  }
}

// Gather: out = [ xyz[b][idx[b][s]][c] (B*S*3) , feat[b][idx[b][s]][:] (B*S*C) ]
__global__ void gather_kernel(const float* __restrict__ xyz,
                              const float* __restrict__ feat,
                              const int* __restrict__ idx,
                              float* __restrict__ out,
                              int B, int N, int S, int C) {
  const int c4pr = C >> 2;          // float4s per feat row
  const int nf4 = B * S * c4pr;     // total float4s of feat output
  int tid = blockIdx.x * blockDim.x + threadIdx.x;
  if (tid < nf4) {
    int c4 = tid % c4pr;
    int bs = tid / c4pr;
    int s = bs % S, b = bs / S;
    int p = idx[b * S + s];
    const float4* src = (const float4*)(feat + ((size_t)b * N + p) * C);
    float4* dst = (float4*)(out + (size_t)B * S * 3 + ((size_t)bs) * C);
    dst[c4] = src[c4];
  } else {
    int t2 = tid - nf4;
    int nxyz = B * S * 3;
    if (t2 < nxyz) {
      int c = t2 % 3;
      int bs = t2 / 3;
      int s = bs % S, b = bs / S;
      int p = idx[b * S + s];
      out[t2] = xyz[((size_t)b * N + p) * 3 + c];
    }
  }
}

extern "C" void kernel_launch(void* const* d_in, const int* in_sizes, int n_in,
                              void* d_out, int out_size, void* d_ws, size_t ws_size,
                              hipStream_t stream) {
  const float* xyz = (const float*)d_in[0];
  const float* feat = (const float*)d_in[1];
  float* out = (float*)d_out;

  const int B = 32;
  const int N = in_sizes[0] / (B * 3);        // 16384
  const int C = in_sizes[1] / (B * N);        // 128
  const int S = N / 4;                        // nsample = 0.25 * N = 4096

  int* d_idx = (int*)d_ws;  // B*S int32

  fps_kernel<<<B, FPS_THREADS, 0, stream>>>(xyz, d_idx, N, S);

  int total = B * S * (C >> 2) + B * S * 3;
  int blocks = (total + 255) / 256;
  gather_kernel<<<blocks, 256, 0, stream>>>(xyz, feat, d_idx, out, B, N, S, C);
}

// Round 13
// 5908.309 us; speedup vs baseline: 1.3712x; 1.3712x over previous
//
#include <hip/hip_runtime.h>
#include <hip/hip_bf16.h>
#include <cfloat>

// FPS matching the np reference bit-exactly (R7: PASS, absmax 0).
// FROZEN per-point arithmetic: dx=px-cx; y2=dy*dy; inner=fma(dx,dx,y2);
// d=fma(dz,dz,inner); nd=fminf(dist,d); winner=(max value, smallest index).
// R13: R12 proved VALU issue is NOT binding (38% fewer VALU cycles, time
// +11%) -> latency/DS-chain bound. Also R8-R12: at 1024 thr the allocator
// pins to the 64-VGPR tier and spills any big state. New shape: 512 thr x
// 32 pts/thread, ALL state in registers (amdgpu_waves_per_eu(2,2) -> 256
// budget), zero per-step LDS coord traffic, 8-wave barrier.

#define FPS_THREADS 512

#define REP32(M) M(0) M(1) M(2) M(3) M(4) M(5) M(6) M(7) \
                 M(8) M(9) M(10) M(11) M(12) M(13) M(14) M(15) \
                 M(16) M(17) M(18) M(19) M(20) M(21) M(22) M(23) \
                 M(24) M(25) M(26) M(27) M(28) M(29) M(30) M(31)

__global__ __launch_bounds__(FPS_THREADS, 2)
__attribute__((amdgpu_waves_per_eu(2, 2)))
void fps_kernel(const float* __restrict__ xyz, int* __restrict__ out_idx,
                int N, int S) {
#pragma clang fp contract(off)
  const int b = blockIdx.x;
  const int t = threadIdx.x;
  const float* xb = xyz + (size_t)b * N * 3;

#define DECLP(k) float px##k, py##k, pz##k, ds##k;
  REP32(DECLP)

#define LOADP(k) { int p = (k) * FPS_THREADS + t;      \
    px##k = xb[(size_t)p * 3 + 0];                     \
    py##k = xb[(size_t)p * 3 + 1];                     \
    pz##k = xb[(size_t)p * 3 + 2];                     \
    ds##k = FLT_MAX; }
  REP32(LOADP)

  __shared__ unsigned long long s_k[2][FPS_THREADS / 64];

  const int wave = t >> 6;
  const int lane = t & 63;
  const unsigned invt = 0xFFFFFFFFu - (unsigned)t;
  int farthest = 0;

  for (int s = 0; s < S; ++s) {
    if (t == 0) out_idx[(size_t)b * S + s] = farthest;

    // centroid: block-uniform index -> scalar loads (L2-resident)
    int f = __builtin_amdgcn_readfirstlane(farthest);
    float cx = xb[(size_t)f * 3 + 0];
    float cy = xb[(size_t)f * 3 + 1];
    float cz = xb[(size_t)f * 3 + 2];

    float bestv = -1.0f;
    int bestk = 0;   // k index: cndmask with inline constant (k < 32)

    // FROZEN reference arithmetic (LLVM DAG contraction form):
#define STEPP(k) {                                               \
    float dx = px##k - cx;                                       \
    float dy = py##k - cy;                                       \
    float dz = pz##k - cz;                                       \
    float y2 = dy * dy;                                          \
    float inner = __builtin_fmaf(dx, dx, y2);                    \
    float dd = __builtin_fmaf(dz, dz, inner);                    \
    float nd = fminf(ds##k, dd);                                 \
    ds##k = nd;                                                  \
    if (nd > bestv) { bestv = nd; bestk = (k); } }
    REP32(STEPP)

    // inverted index once per step: inv = (0xFFFFFFFF - t) - k*512
    unsigned bestinv = invt - (unsigned)(bestk * FPS_THREADS);
    unsigned long long bestkkey =
        ((unsigned long long)__float_as_uint(bestv) << 32) |
        (unsigned long long)bestinv;

    // wave-level butterfly max over packed keys (dist >= 0 =>
    // u64 max == (max value, then smallest index))
#pragma unroll
    for (int off = 32; off > 0; off >>= 1) {
      unsigned long long ok = __shfl_xor(bestkkey, off, 64);
      if (ok > bestkkey) bestkkey = ok;
    }

    // single barrier per step: parity double-buffer
    const int par = s & 1;
    if (lane == 0) s_k[par][wave] = bestkkey;
    __syncthreads();

    unsigned long long bk = s_k[par][0];
#pragma unroll
    for (int w = 1; w < FPS_THREADS / 64; ++w) {
      unsigned long long ok = s_k[par][w];
      if (ok > bk) bk = ok;
    }
    farthest = (int)(0xFFFFFFFFu - (unsigned)(bk & 0xFFFFFFFFu));
  }
}

// Gather: out = [ xyz[b][idx[b][s]][c] (B*S*3) , feat[b][idx[b][s]][:] (B*S*C) ]
__global__ void gather_kernel(const float* __restrict__ xyz,
                              const float* __restrict__ feat,
                              const int* __restrict__ idx,
                              float* __restrict__ out,
                              int B, int N, int S, int C) {
  const int c4pr = C >> 2;          // float4s per feat row
  const int nf4 = B * S * c4pr;     // total float4s of feat output
  int tid = blockIdx.x * blockDim.x + threadIdx.x;
  if (tid < nf4) {
    int c4 = tid % c4pr;
    int bs = tid / c4pr;
    int s = bs % S, b = bs / S;
    int p = idx[b * S + s];
    const float4* src = (const float4*)(feat + ((size_t)b * N + p) * C);
    float4* dst = (float4*)(out + (size_t)B * S * 3 + ((size_t)bs) * C);
    dst[c4] = src[c4];
  } else {
    int t2 = tid - nf4;
    int nxyz = B * S * 3;
    if (t2 < nxyz) {
      int c = t2 % 3;
      int bs = t2 / 3;
      int s = bs % S, b = bs / S;
      int p = idx[b * S + s];
      out[t2] = xyz[((size_t)b * N + p) * 3 + c];
    }
  }
}

extern "C" void kernel_launch(void* const* d_in, const int* in_sizes, int n_in,
                              void* d_out, int out_size, void* d_ws, size_t ws_size,
                              hipStream_t stream) {
  const float* xyz = (const float*)d_in[0];
  const float* feat = (const float*)d_in[1];
  float* out = (float*)d_out;

  const int B = 32;
  const int N = in_sizes[0] / (B * 3);        // 16384
  const int C = in_sizes[1] / (B * N);        // 128
  const int S = N / 4;                        // nsample = 0.25 * N = 4096

  int* d_idx = (int*)d_ws;  // B*S int32

  fps_kernel<<<B, FPS_THREADS, 0, stream>>>(xyz, d_idx, N, S);

  int total = B * S * (C >> 2) + B * S * 3;
  int blocks = (total + 255) / 256;
  gather_kernel<<<blocks, 256, 0, stream>>>(xyz, feat, d_idx, out, B, N, S, C);
}